// Round 6
// baseline (61.277 us; speedup 1.0000x reference)
//
#include <hip/hip_runtime.h>

#define BB 2
#define NN 1024
#define FF 128
#define H1 64
#define H2 32
#define MAGIC 0x5F3E2A19u

typedef __attribute__((ext_vector_type(8))) _Float16 half8;   // 8 f16 (4 VGPR)
typedef __attribute__((ext_vector_type(16))) float f32x16;    // 32x32 MFMA acc

// e = relu(a + b) in packed f16: 4x v_pk_add_f16 + 4x v_pk_max_f16
__device__ inline half8 addrelu8(half8 a, half8 b) {
    half8 s = a + b;
    const half8 z = {};
    return __builtin_elementwise_max(s, z);
}

// ---------------------------------------------------------------------------
// Single-launch fused kernel, point-to-point flag handshake (no grid barrier
// — R3 showed cg::grid().sync() costs ~115us). R4's version of this spun on
// ACQUIRE-scope atomic loads: each poll iteration emits cache invalidations,
// and ~1000 blocks polling produced an invalidation storm that stretched the
// kernel to ~88us (MFMA-busy still 3.2us = work model). This round uses the
// correct idiom: RELAXED polls + ONE acquire fence per block after all flags
// are seen (__builtin_amdgcn_fence — __hip_atomic_fence does not exist in
// this ROCm, R5 compile fail); producer side relies on the RELEASE store
// alone. Producer-independent loads (W2/b2/W3/b3) hoisted above the poll.
// Deadlock-free by construction: __launch_bounds__(256,4) (60 VGPR, 10.25KB
// LDS) -> 4 blocks/CU -> all 1024 blocks co-resident (R4 ran: confirmed).
// ---------------------------------------------------------------------------
__global__ __launch_bounds__(256, 4) void fused_kernel(
    const float* __restrict__ x, const float* __restrict__ W1,
    const float* __restrict__ b1, const float* __restrict__ W2,
    const float* __restrict__ b2, const float* __restrict__ W3,
    const float* __restrict__ b3,
    _Float16* __restrict__ pj, _Float16* __restrict__ pib,
    unsigned int* __restrict__ flags, float* __restrict__ out)
{
    // phase-1 view: xs[4][128] (2KB) + red[4][4][64][2] (8KB) = 10.25KB
    // phase-2 view: plds[64][64] f16 (8KB) — overlaid, separated by barrier
    __shared__ __align__(16) char smem[10240];
    float (*xs)[FF]          = (float(*)[FF])smem;
    float (*red)[4][H1][2]   = (float(*)[4][H1][2])(smem + 2048);
    _Float16 (*plds)[H1]     = (_Float16(*)[H1])smem;

    const int tid  = threadIdx.x;
    const int lane = tid & 63;
    const int wv   = tid >> 6;
    const int bid  = blockIdx.x;

    // ============ phase 1: pj/pib precompute (blocks 0..511) ==============
    if (bid < 512) {
        const int h    = lane;
        const int row0 = bid * 4;                 // global row (b*NN folded in)

        const float* xbase = x + (size_t)row0 * FF;
        for (int t = tid; t < 4 * FF; t += 256)
            xs[t >> 7][t & 127] = xbase[t];
        __syncthreads();

        float accj[4] = {}, acci[4] = {};
        const int k0 = wv * 32;
        #pragma unroll 8
        for (int kk = 0; kk < 32; ++kk) {
            const int k = k0 + kk;
            const float wj = W1[k * H1 + h];          // coalesced, once/block
            const float wi = W1[(FF + k) * H1 + h];
            #pragma unroll
            for (int r = 0; r < 4; ++r) {
                const float xv = xs[r][k];            // wave-uniform broadcast
                accj[r] = fmaf(xv, wj, accj[r]);
                acci[r] = fmaf(xv, wi, acci[r]);
            }
        }
        #pragma unroll
        for (int r = 0; r < 4; ++r) {
            red[wv][r][h][0] = accj[r];
            red[wv][r][h][1] = acci[r];
        }
        __syncthreads();

        #pragma unroll
        for (int half = 0; half < 2; ++half) {
            const int o = tid + half * 256;
            const int c = o & 1, hh = (o >> 1) & 63, r = o >> 7;
            const float s = red[0][r][hh][c] + red[1][r][hh][c]
                          + red[2][r][hh][c] + red[3][r][hh][c];
            const size_t idx = (size_t)(row0 + r) * H1 + hh;
            if (c == 0) pj[idx]  = (_Float16)s;
            else        pib[idx] = (_Float16)(s + b1[hh]);
        }

        // publish: __syncthreads drains every wave's stores (vmcnt 0 before
        // s_barrier), then ONE release store orders them for consumers.
        __syncthreads();
        if (tid == 0)
            __hip_atomic_store(&flags[bid], MAGIC,
                               __ATOMIC_RELEASE, __HIP_MEMORY_SCOPE_AGENT);
    }

    // ============ phase 2: edge tile (all 1024 blocks) ====================
    const int b   = bid >> 9;                 // 512 blocks per batch
    const int rem = bid & 511;
    const int i0  = (rem >> 5) * 64;          // 16 i-tiles (64 rows each)
    const int j0  = (rem & 31) * 32;          // 32 j-tiles (32 cols each)
    const int jn  = lane & 31;                // m/n lane index
    const int hi  = lane >> 5;                // k-group half

    // ---- producer-independent loads, hoisted above the poll ----
    // A-frags straight from W2 (L2-resident, coalesced along jn):
    //   wa[c][e] = (f16)W2[16c + hi*8 + e][jn]
    half8 wa[4];
    #pragma unroll
    for (int c4 = 0; c4 < 4; ++c4)
        #pragma unroll
        for (int e = 0; e < 8; ++e)
            wa[c4][e] = (_Float16)W2[(16 * c4 + hi * 8 + e) * H2 + jn];

    f32x16 ci;
    float w3r[16];
    #pragma unroll
    for (int r = 0; r < 16; ++r) {           // D row mapping [m74/m101]
        const int row = (r & 3) + 8 * (r >> 2) + 4 * hi;
        ci[r]  = b2[row];
        w3r[r] = W3[row];
    }
    const float b3v = b3[0];

    // ---- wait for the 24 producer row-blocks this tile reads (i:16,j:8) --
    {
        const int fi0 = (b * NN + i0) >> 2;
        const int fj0 = (b * NN + j0) >> 2;
        if (tid < 24) {
            const int f = tid < 16 ? fi0 + tid : fj0 + (tid - 16);
            while (__hip_atomic_load(&flags[f], __ATOMIC_RELAXED,
                                     __HIP_MEMORY_SCOPE_AGENT) != MAGIC)
                __builtin_amdgcn_s_sleep(4);
        }
        __syncthreads();   // all flags seen; also separates LDS overlay
        // ONE acquire fence per block: pairs with producers' release stores.
        __builtin_amdgcn_fence(__ATOMIC_ACQUIRE, "agent");
    }

    // ---- async stage: wave's 16 pib rows (2 KB) into LDS, linear dest ----
    {
        const _Float16* src = pib + (size_t)(b * NN + i0 + wv * 16) * H1 + lane * 8;
        char* dst = (char*)&plds[wv * 16][0];
        #pragma unroll
        for (int r = 0; r < 2; ++r)
            __builtin_amdgcn_global_load_lds(
                (const __attribute__((address_space(1))) void*)(src + r * 512),
                (__attribute__((address_space(3))) void*)(dst + r * 1024),
                16, 0, 0);
    }

    // B-frags (pj side), pinned: row j0+jn, k-slices 16c + hi*8
    const _Float16* pr = pj + (size_t)(b * NN + j0 + jn) * H1 + hi * 8;
    const half8 qj0 = *(const half8*)(pr);
    const half8 qj1 = *(const half8*)(pr + 16);
    const half8 qj2 = *(const half8*)(pr + 32);
    const half8 qj3 = *(const half8*)(pr + 48);

    __syncthreads();   // drains vmcnt (staging) then barrier

    const int srow = wv * 16;
    const _Float16* irbase = &plds[srow][0] + hi * 8;
    float* obase = out + (size_t)(b * NN + i0 + srow) * NN + j0 + jn;

    // prologue: load row 0 of this wave's 16
    half8 c0 = *(const half8*)(irbase);
    half8 c1 = *(const half8*)(irbase + 16);
    half8 c2 = *(const half8*)(irbase + 32);
    half8 c3 = *(const half8*)(irbase + 48);
    half8 n0, n1, n2, n3;
    float pe = 0.f;

    #pragma unroll 1
    for (int t = 0; t < 16; ++t) {
        if (t < 15) {                        // 1-row LDS lookahead
            const _Float16* ir = irbase + (t + 1) * H1;
            n0 = *(const half8*)(ir);
            n1 = *(const half8*)(ir + 16);
            n2 = *(const half8*)(ir + 32);
            n3 = *(const half8*)(ir + 48);
        }
        half8 e0 = addrelu8(qj0, c0);        // c* dies into e* (no reg growth)
        half8 e1 = addrelu8(qj1, c1);
        half8 e2 = addrelu8(qj2, c2);
        half8 e3 = addrelu8(qj3, c3);
        f32x16 d;
        d = __builtin_amdgcn_mfma_f32_32x32x16_f16(wa[0], e0, ci, 0, 0, 0);
        d = __builtin_amdgcn_mfma_f32_32x32x16_f16(wa[1], e1, d,  0, 0, 0);
        d = __builtin_amdgcn_mfma_f32_32x32x16_f16(wa[2], e2, d,  0, 0, 0);
        d = __builtin_amdgcn_mfma_f32_32x32x16_f16(wa[3], e3, d,  0, 0, 0);
        float p0 = 0.f, p1 = 0.f, p2 = 0.f, p3 = 0.f;   // 4 parallel chains
        #pragma unroll
        for (int r = 0; r < 4; ++r) {
            p0 = fmaf(fmaxf(d[r],      0.f), w3r[r],      p0);
            p1 = fmaf(fmaxf(d[4 + r],  0.f), w3r[4 + r],  p1);
            p2 = fmaf(fmaxf(d[8 + r],  0.f), w3r[8 + r],  p2);
            p3 = fmaf(fmaxf(d[12 + r], 0.f), w3r[12 + r], p3);
        }
        float p = (p0 + p1) + (p2 + p3);
        p += __shfl_xor(p, 32);              // lane-halves hold complementary rows
        if (t & 1) {                         // store a 2-row pair, full-wave
            float v = hi ? p : pe;           // hi half stores the odd row
            obase[(size_t)(t - 1 + hi) * NN] = v + b3v;
        } else {
            pe = p;
        }
        c0 = n0; c1 = n1; c2 = n2; c3 = n3;  // rotate pipeline regs
    }
}

extern "C" void kernel_launch(void* const* d_in, const int* in_sizes, int n_in,
                              void* d_out, int out_size, void* d_ws, size_t ws_size,
                              hipStream_t stream) {
    const float* x  = (const float*)d_in[0];
    // d_in[1] = adj (UNUSED by reference), d_in[2] = mask (UNUSED)
    const float* W1 = (const float*)d_in[3];
    const float* b1 = (const float*)d_in[4];
    const float* W2 = (const float*)d_in[5];
    const float* b2 = (const float*)d_in[6];
    const float* W3 = (const float*)d_in[7];
    const float* b3 = (const float*)d_in[8];
    float* out = (float*)d_out;

    _Float16* pj  = (_Float16*)d_ws;                    // B*N*H1 f16 = 256 KB
    _Float16* pib = pj + (size_t)BB * NN * H1;          // B*N*H1 f16 = 256 KB
    unsigned int* flags = (unsigned int*)(pib + (size_t)BB * NN * H1); // 2 KB

    fused_kernel<<<BB * NN / 2, 256, 0, stream>>>(
        x, W1, b1, W2, b2, W3, b3, pj, pib, flags, out);
}

// Round 7
// 32.548 us; speedup vs baseline: 1.8827x; 1.8827x over previous
//
#include <hip/hip_runtime.h>

#define BB 2
#define NN 1024
#define FF 128
#define H1 64
#define H2 32
#define PAD 72   // LDS row stride in f16 (64 + 8): breaks 128B bank alignment

typedef __attribute__((ext_vector_type(8))) _Float16 half8;   // 8 f16 (4 VGPR)
typedef __attribute__((ext_vector_type(16))) float f32x16;    // 32x32 MFMA acc

// e = relu(a + b) in packed f16: 4x v_pk_add_f16 + 4x v_pk_max_f16
__device__ inline half8 addrelu8(half8 a, half8 b) {
    half8 s = a + b;
    const half8 z = {};
    return __builtin_elementwise_max(s, z);
}

// ---------------------------------------------------------------------------
// ZERO-SYNC full fusion. R3/R4/R6 proved any inter-block handshake (coop
// barrier 127us, acquire-poll 88us, relaxed-poll+fence 61us) costs 10-20x
// the actual work (MFMA-busy ~3us in every variant). This version removes
// inter-block communication entirely: each block recomputes the 96
// pj/pib rows ITS tile needs (64 i-rows + 32 j-rows) with 48 extra
// 32x32x16 MFMAs (A = W1 f16 frags, B = x rows gathered from L2-hot
// global), writes them to padded LDS, __syncthreads, then runs the
// proven edge loop sourcing qj/plds from LDS. No flags, no atomics, no
// second launch, no workspace, no co-residency requirement.
// Redundancy cost: +19% MFMA, ~50MB L2-resident x gathers. Accuracy: x,W1
// round to f16 pre-dot (added ~3e-4 abs on pj/pib; downstream f16 h
// rounding still dominates).
// ---------------------------------------------------------------------------
__global__ __launch_bounds__(256, 4) void fused_kernel(
    const float* __restrict__ x, const float* __restrict__ W1,
    const float* __restrict__ b1, const float* __restrict__ W2,
    const float* __restrict__ b2, const float* __restrict__ W3,
    const float* __restrict__ b3, float* __restrict__ out)
{
    __shared__ _Float16 plds[64][PAD];    // pib rows i0..i0+63  (9.2 KB)
    __shared__ _Float16 pjlds[32][PAD];   // pj  rows j0..j0+31  (4.6 KB)

    const int tid  = threadIdx.x;
    const int lane = tid & 63;
    const int wv   = tid >> 6;
    const int bid  = blockIdx.x;

    const int b   = bid >> 9;                 // 512 blocks per batch
    const int rem = bid & 511;
    const int i0  = (rem >> 5) * 64;          // 16 i-tiles (64 rows each)
    const int j0  = (rem & 31) * 32;          // 32 j-tiles (32 cols each)
    const int jn  = lane & 31;                // m/n lane index
    const int hi  = lane >> 5;                // k-group half

    // ============ phase A: in-block precompute of plds/pjlds ==============
    // One unit = 32 rows x 32 h's x K=128 = 8 MFMAs.
    //   A-frag[e] = (f16)W1[koff + k][htile*32 + m]   (m = lane&31)
    //   B-frag[e] = (f16)x[rowbase + m][k],  k = ks*16 + hi*8 + e
    //   D: col = m = row-in-tile, reg r -> h_local = (r&3)+8*(r>>2)+4*hi
    // pj uses W1[:128] (koff=0), pib uses W1[128:] (koff=128) + b1.
    const int m = jn;
    auto gemm_unit = [&](int rowbase, int htile, int koff,
                         _Float16* dstbase, const float* bias) {
        f32x16 acc = {};
        #pragma unroll
        for (int ks = 0; ks < 8; ++ks) {
            const int k0 = ks * 16 + hi * 8;
            half8 af, bf;
            const float* wb = W1 + (size_t)(koff + k0) * H1 + htile * 32 + m;
            #pragma unroll
            for (int e = 0; e < 8; ++e)
                af[e] = (_Float16)wb[(size_t)e * H1];       // coalesced per e
            const float* xb = x + (size_t)(rowbase + m) * FF + k0;
            const float4 x0 = *(const float4*)xb;           // 32B/lane gather
            const float4 x1 = *(const float4*)(xb + 4);     // (L2-hot x)
            bf[0] = (_Float16)x0.x; bf[1] = (_Float16)x0.y;
            bf[2] = (_Float16)x0.z; bf[3] = (_Float16)x0.w;
            bf[4] = (_Float16)x1.x; bf[5] = (_Float16)x1.y;
            bf[6] = (_Float16)x1.z; bf[7] = (_Float16)x1.w;
            acc = __builtin_amdgcn_mfma_f32_32x32x16_f16(af, bf, acc, 0, 0, 0);
        }
        _Float16* drow = dstbase + (size_t)m * PAD;         // D col -> LDS row
        #pragma unroll
        for (int r = 0; r < 16; ++r) {
            const int hl = (r & 3) + 8 * (r >> 2) + 4 * hi; // D row map [m74/m101]
            const int hg = htile * 32 + hl;
            float v = acc[r];
            if (bias) v += bias[hg];
            drow[hg] = (_Float16)v;
        }
    };
    if (wv < 2) {
        gemm_unit(b * NN + i0,      wv,     128, &plds[0][0],  b1);  // pib r0
        gemm_unit(b * NN + j0,      wv,     0,   &pjlds[0][0], nullptr); // pj
    } else {
        gemm_unit(b * NN + i0 + 32, wv - 2, 128, &plds[32][0], b1);  // pib r1
    }

    // ============ per-wave edge init (weights straight from global) =======
    // A-frags: wa[c][e] = (f16)W2[16c + hi*8 + e][jn]  (coalesced along jn)
    half8 wa[4];
    #pragma unroll
    for (int c4 = 0; c4 < 4; ++c4)
        #pragma unroll
        for (int e = 0; e < 8; ++e)
            wa[c4][e] = (_Float16)W2[(16 * c4 + hi * 8 + e) * H2 + jn];

    f32x16 ci;
    float w3r[16];
    #pragma unroll
    for (int r = 0; r < 16; ++r) {           // D row mapping [m74/m101]
        const int row = (r & 3) + 8 * (r >> 2) + 4 * hi;
        ci[r]  = b2[row];
        w3r[r] = W3[row];
    }
    const float b3v = b3[0];

    __syncthreads();   // phase A LDS writes visible to all waves

    // B-frags (pj side) from LDS: row j0+jn, k-slices 16c + hi*8
    const _Float16* pr = &pjlds[jn][hi * 8];
    const half8 qj0 = *(const half8*)(pr);
    const half8 qj1 = *(const half8*)(pr + 16);
    const half8 qj2 = *(const half8*)(pr + 32);
    const half8 qj3 = *(const half8*)(pr + 48);

    // ============ phase B: 16 row-steps, 1-row LDS lookahead ==============
    const int srow = wv * 16;
    const _Float16* irbase = &plds[srow][hi * 8];
    float* obase = out + (size_t)(b * NN + i0 + srow) * NN + j0 + jn;

    half8 c0 = *(const half8*)(irbase);
    half8 c1 = *(const half8*)(irbase + 16);
    half8 c2 = *(const half8*)(irbase + 32);
    half8 c3 = *(const half8*)(irbase + 48);
    half8 n0, n1, n2, n3;
    float pe = 0.f;

    #pragma unroll 1
    for (int t = 0; t < 16; ++t) {
        if (t < 15) {                        // 1-row LDS lookahead
            const _Float16* ir = irbase + (t + 1) * PAD;
            n0 = *(const half8*)(ir);
            n1 = *(const half8*)(ir + 16);
            n2 = *(const half8*)(ir + 32);
            n3 = *(const half8*)(ir + 48);
        }
        half8 e0 = addrelu8(qj0, c0);        // c* dies into e* (no reg growth)
        half8 e1 = addrelu8(qj1, c1);
        half8 e2 = addrelu8(qj2, c2);
        half8 e3 = addrelu8(qj3, c3);
        f32x16 d;
        d = __builtin_amdgcn_mfma_f32_32x32x16_f16(wa[0], e0, ci, 0, 0, 0);
        d = __builtin_amdgcn_mfma_f32_32x32x16_f16(wa[1], e1, d,  0, 0, 0);
        d = __builtin_amdgcn_mfma_f32_32x32x16_f16(wa[2], e2, d,  0, 0, 0);
        d = __builtin_amdgcn_mfma_f32_32x32x16_f16(wa[3], e3, d,  0, 0, 0);
        float p0 = 0.f, p1 = 0.f, p2 = 0.f, p3 = 0.f;   // 4 parallel chains
        #pragma unroll
        for (int r = 0; r < 4; ++r) {
            p0 = fmaf(fmaxf(d[r],      0.f), w3r[r],      p0);
            p1 = fmaf(fmaxf(d[4 + r],  0.f), w3r[4 + r],  p1);
            p2 = fmaf(fmaxf(d[8 + r],  0.f), w3r[8 + r],  p2);
            p3 = fmaf(fmaxf(d[12 + r], 0.f), w3r[12 + r], p3);
        }
        float p = (p0 + p1) + (p2 + p3);
        p += __shfl_xor(p, 32);              // lane-halves hold complementary rows
        if (t & 1) {                         // store a 2-row pair, full-wave
            float v = hi ? p : pe;           // hi half stores the odd row
            obase[(size_t)(t - 1 + hi) * NN] = v + b3v;
        } else {
            pe = p;
        }
        c0 = n0; c1 = n1; c2 = n2; c3 = n3;  // rotate pipeline regs
    }
}

extern "C" void kernel_launch(void* const* d_in, const int* in_sizes, int n_in,
                              void* d_out, int out_size, void* d_ws, size_t ws_size,
                              hipStream_t stream) {
    const float* x  = (const float*)d_in[0];
    // d_in[1] = adj (UNUSED by reference), d_in[2] = mask (UNUSED)
    const float* W1 = (const float*)d_in[3];
    const float* b1 = (const float*)d_in[4];
    const float* W2 = (const float*)d_in[5];
    const float* b2 = (const float*)d_in[6];
    const float* W3 = (const float*)d_in[7];
    const float* b3 = (const float*)d_in[8];
    float* out = (float*)d_out;

    // single self-sufficient launch; workspace unused
    fused_kernel<<<BB * NN / 2, 256, 0, stream>>>(
        x, W1, b1, W2, b2, W3, b3, out);
}

// Round 8
// 26.149 us; speedup vs baseline: 2.3433x; 1.2447x over previous
//
#include <hip/hip_runtime.h>

#define BB 2
#define NN 1024
#define FF 128
#define H1 64
#define H2 32
#define XPAD 136  // x-row stride in f16 (128+8): 272B = 16B-aligned, 4-way max
#define PAD 72    // p-row stride in f16 (64+8): 144B = 16B-aligned

typedef __attribute__((ext_vector_type(4))) _Float16 half4;   // 4 f16 (8B)
typedef __attribute__((ext_vector_type(8))) _Float16 half8;   // 8 f16 (4 VGPR)
typedef __attribute__((ext_vector_type(16))) float f32x16;    // 32x32 MFMA acc

// e = relu(a + b) in packed f16: 4x v_pk_add_f16 + 4x v_pk_max_f16
__device__ inline half8 addrelu8(half8 a, half8 b) {
    half8 s = a + b;
    const half8 z = {};
    return __builtin_elementwise_max(s, z);
}

// ---------------------------------------------------------------------------
// ZERO-SYNC full fusion, v2. R7 (32.5us) proved the structure but its phase A
// read x with per-lane-row scattered float4 gathers — 64 distinct lines per
// instruction, cold after the harness's 256MB poison-fill sweeps L2/L3 ->
// HBM-latency-bound (~25us of the 32.5). This version stages the block's 96
// x-rows into LDS with a dense COALESCED dependency-free loop (12 iters of
// wave-wide 128B-line loads, f32->f16 once), then builds phase-A B-frags
// from LDS. Phase-A math and all of phase B are byte-identical to R7.
// R2-chain accounting says E (edge phase) is only ~4-6us; single launch has
// no inter-dispatch gap (R6: bench==kernel), so this should expose it.
// ---------------------------------------------------------------------------
__global__ __launch_bounds__(256, 4) void fused_kernel(
    const float* __restrict__ x, const float* __restrict__ W1,
    const float* __restrict__ b1, const float* __restrict__ W2,
    const float* __restrict__ b2, const float* __restrict__ W3,
    const float* __restrict__ b3, float* __restrict__ out)
{
    __shared__ __align__(16) _Float16 xlds[96][XPAD];  // 26.1 KB staged x (f16)
    __shared__ __align__(16) _Float16 plds[64][PAD];   // 9.2 KB pib rows
    __shared__ __align__(16) _Float16 pjlds[32][PAD];  // 4.6 KB pj rows
    // total 39.9 KB -> exactly 4 blocks/CU

    const int tid  = threadIdx.x;
    const int lane = tid & 63;
    const int wv   = tid >> 6;
    const int bid  = blockIdx.x;

    const int b   = bid >> 9;                 // 512 blocks per batch
    const int rem = bid & 511;
    const int i0  = (rem >> 5) * 64;          // 16 i-tiles (64 rows each)
    const int j0  = (rem & 31) * 32;          // 32 j-tiles (32 cols each)
    const int jn  = lane & 31;                // m/n lane index
    const int hi  = lane >> 5;                // k-group half
    const int m   = jn;

    // ============ stage: 96 x-rows -> xlds (coalesced, f16) ===============
    // rows 0..63 = i-rows i0..i0+63; rows 64..95 = j-rows j0..j0+31.
    {
        const int xb_i = b * NN + i0, xb_j = b * NN + j0 - 64;
        #pragma unroll
        for (int it = 0; it < 12; ++it) {
            const int idx = tid + it * 256;
            const int row = idx >> 5, c4 = (idx & 31) * 4;
            const int gr  = (row < 64 ? xb_i : xb_j) + row;
            const float4 v = *(const float4*)(x + (size_t)gr * FF + c4);
            half4 hv = {(_Float16)v.x, (_Float16)v.y,
                        (_Float16)v.z, (_Float16)v.w};
            *(half4*)&xlds[row][c4] = hv;
        }
    }
    __syncthreads();

    // ============ phase A: 6 gemm units (32 rows x 32 h each) =============
    //   A-frag[e] = (f16)W1[koff + k][htile*32 + m]   (L2-hot, coalesced)
    //   B-frag    = xlds[xrow0 + m][k0..k0+7]         (ds_read_b128)
    //   D: col = m = row-in-tile, reg r -> h_local = (r&3)+8*(r>>2)+4*hi
    auto gemm_unit = [&](int xrow0, int htile, int koff,
                         _Float16* dstbase, const float* bias) {
        f32x16 acc = {};
        #pragma unroll
        for (int ks = 0; ks < 8; ++ks) {
            const int k0 = ks * 16 + hi * 8;
            half8 af;
            const float* wb = W1 + (size_t)(koff + k0) * H1 + htile * 32 + m;
            #pragma unroll
            for (int e = 0; e < 8; ++e)
                af[e] = (_Float16)wb[(size_t)e * H1];     // coalesced per e
            const half8 bf = *(const half8*)&xlds[xrow0 + m][k0];
            acc = __builtin_amdgcn_mfma_f32_32x32x16_f16(af, bf, acc, 0, 0, 0);
        }
        _Float16* drow = dstbase + (size_t)m * PAD;       // D col -> LDS row
        #pragma unroll
        for (int q = 0; q < 4; ++q) {                     // packed b64 stores
            half4 hv;
            #pragma unroll
            for (int jj = 0; jj < 4; ++jj) {
                const int r  = q * 4 + jj;                // hl=(r&3)+8(r>>2)+4hi
                const int hg = htile * 32 + 8 * q + 4 * hi + jj;
                float v = acc[r];
                if (bias) v += bias[hg];
                hv[jj] = (_Float16)v;
            }
            *(half4*)(drow + htile * 32 + 8 * q + 4 * hi) = hv;
        }
    };
    if (wv == 0) {
        gemm_unit(0,  0, FF, &plds[0][0],  b1);       // pib rows 0-31, h 0-31
        gemm_unit(64, 0, 0,  &pjlds[0][0], nullptr);  // pj  rows 0-31, h 0-31
    } else if (wv == 1) {
        gemm_unit(0,  1, FF, &plds[0][0],  b1);       // pib rows 0-31, h 32-63
        gemm_unit(64, 1, 0,  &pjlds[0][0], nullptr);  // pj  rows 0-31, h 32-63
    } else if (wv == 2) {
        gemm_unit(32, 0, FF, &plds[32][0], b1);       // pib rows 32-63, h 0-31
    } else {
        gemm_unit(32, 1, FF, &plds[32][0], b1);       // pib rows 32-63, h 32-63
    }

    // ============ per-wave edge init (weights straight from global) =======
    half8 wa[4];
    #pragma unroll
    for (int c4 = 0; c4 < 4; ++c4)
        #pragma unroll
        for (int e = 0; e < 8; ++e)
            wa[c4][e] = (_Float16)W2[(16 * c4 + hi * 8 + e) * H2 + jn];

    f32x16 ci;
    float w3r[16];
    #pragma unroll
    for (int r = 0; r < 16; ++r) {           // D row mapping [m74/m101]
        const int row = (r & 3) + 8 * (r >> 2) + 4 * hi;
        ci[r]  = b2[row];
        w3r[r] = W3[row];
    }
    const float b3v = b3[0];

    __syncthreads();   // phase A LDS writes visible to all waves

    // B-frags (pj side) from LDS: row j0+jn, k-slices 16c + hi*8
    const _Float16* pr = &pjlds[jn][hi * 8];
    const half8 qj0 = *(const half8*)(pr);
    const half8 qj1 = *(const half8*)(pr + 16);
    const half8 qj2 = *(const half8*)(pr + 32);
    const half8 qj3 = *(const half8*)(pr + 48);

    // ============ phase B: 16 row-steps, 1-row LDS lookahead ==============
    const int srow = wv * 16;
    const _Float16* irbase = &plds[srow][hi * 8];
    float* obase = out + (size_t)(b * NN + i0 + srow) * NN + j0 + jn;

    half8 c0 = *(const half8*)(irbase);
    half8 c1 = *(const half8*)(irbase + 16);
    half8 c2 = *(const half8*)(irbase + 32);
    half8 c3 = *(const half8*)(irbase + 48);
    half8 n0, n1, n2, n3;
    float pe = 0.f;

    #pragma unroll 1
    for (int t = 0; t < 16; ++t) {
        if (t < 15) {                        // 1-row LDS lookahead
            const _Float16* ir = irbase + (t + 1) * PAD;
            n0 = *(const half8*)(ir);
            n1 = *(const half8*)(ir + 16);
            n2 = *(const half8*)(ir + 32);
            n3 = *(const half8*)(ir + 48);
        }
        half8 e0 = addrelu8(qj0, c0);        // c* dies into e* (no reg growth)
        half8 e1 = addrelu8(qj1, c1);
        half8 e2 = addrelu8(qj2, c2);
        half8 e3 = addrelu8(qj3, c3);
        f32x16 d;
        d = __builtin_amdgcn_mfma_f32_32x32x16_f16(wa[0], e0, ci, 0, 0, 0);
        d = __builtin_amdgcn_mfma_f32_32x32x16_f16(wa[1], e1, d,  0, 0, 0);
        d = __builtin_amdgcn_mfma_f32_32x32x16_f16(wa[2], e2, d,  0, 0, 0);
        d = __builtin_amdgcn_mfma_f32_32x32x16_f16(wa[3], e3, d,  0, 0, 0);
        float p0 = 0.f, p1 = 0.f, p2 = 0.f, p3 = 0.f;   // 4 parallel chains
        #pragma unroll
        for (int r = 0; r < 4; ++r) {
            p0 = fmaf(fmaxf(d[r],      0.f), w3r[r],      p0);
            p1 = fmaf(fmaxf(d[4 + r],  0.f), w3r[4 + r],  p1);
            p2 = fmaf(fmaxf(d[8 + r],  0.f), w3r[8 + r],  p2);
            p3 = fmaf(fmaxf(d[12 + r], 0.f), w3r[12 + r], p3);
        }
        float p = (p0 + p1) + (p2 + p3);
        p += __shfl_xor(p, 32);              // lane-halves hold complementary rows
        if (t & 1) {                         // store a 2-row pair, full-wave
            float v = hi ? p : pe;           // hi half stores the odd row
            obase[(size_t)(t - 1 + hi) * NN] = v + b3v;
        } else {
            pe = p;
        }
        c0 = n0; c1 = n1; c2 = n2; c3 = n3;  // rotate pipeline regs
    }
}

extern "C" void kernel_launch(void* const* d_in, const int* in_sizes, int n_in,
                              void* d_out, int out_size, void* d_ws, size_t ws_size,
                              hipStream_t stream) {
    const float* x  = (const float*)d_in[0];
    // d_in[1] = adj (UNUSED by reference), d_in[2] = mask (UNUSED)
    const float* W1 = (const float*)d_in[3];
    const float* b1 = (const float*)d_in[4];
    const float* W2 = (const float*)d_in[5];
    const float* b2 = (const float*)d_in[6];
    const float* W3 = (const float*)d_in[7];
    const float* b3 = (const float*)d_in[8];
    float* out = (float*)d_out;

    // single self-sufficient launch; workspace unused
    fused_kernel<<<BB * NN / 2, 256, 0, stream>>>(
        x, W1, b1, W2, b2, W3, b3, out);
}